// Round 1
// baseline (51081.491 us; speedup 1.0000x reference)
//
#include <hip/hip_runtime.h>
#include <math.h>

#define VOCAB 2048
#define EMB   512
#define HID   1024
#define TX    256
#define BATCH 64

// ---------------- ws layout (floats) ----------------
// xeT_all : [TX][EMB][BATCH]  = 8,388,608  (32 MB)
// h1T_all : [TX][HID][BATCH]  = 16,777,216 (64 MB)
// states  : h0T[2], h1T[2], c0T, c1T  (6 * 65,536)
#define XET_OFF    0
#define H1ALL_OFF  (8388608)
#define STATE_OFF  (H1ALL_OFF + 16777216)
// state sub-offsets (in floats, relative to STATE_OFF)
#define HB_ (HID * BATCH)   // 65536

// ---------------------------------------------------------------------------
// Embedding gather, transposed: xeT[t][e][b] = emb[x[b][t]][e]
// ---------------------------------------------------------------------------
__global__ __launch_bounds__(256) void embed_t_kernel(
    const int* __restrict__ x, const float* __restrict__ emb,
    float* __restrict__ xeT)
{
    int flat = blockIdx.x * 256 + threadIdx.x;    // TX*EMB*BATCH threads
    int b = flat & 63;
    int e = (flat >> 6) & (EMB - 1);
    int t = flat >> 15;                            // /(64*512)
    int idx = x[b * TX + t];
    xeT[flat] = emb[idx * EMB + e];
}

// ---------------------------------------------------------------------------
// One LSTM layer for one timestep, fused GEMM + cell update.
// States are stored transposed: hT[k][b], cT[k][b].
// Block = 256 threads = 4 waves; wave g computes gate g for 4 hidden units
// (k0..k0+3) across all 64 batches (lane = batch). 256 blocks cover H=1024.
// gates = W_ih · xT + W_hh · hT_in + b_ih + b_hh   (j = g*H + k)
// ---------------------------------------------------------------------------
#define CK 128   // K-chunk staged in LDS

__global__ __launch_bounds__(256) void lstm_step_kernel(
    const float* __restrict__ xT, int Kx,          // [Kx][64]
    const float* __restrict__ hT_in,               // [1024][64]
    const float* __restrict__ W_ih,                // [4H][Kx]
    const float* __restrict__ W_hh,                // [4H][1024]
    const float* __restrict__ b_ih,
    const float* __restrict__ b_hh,
    float* __restrict__ hT_out,                    // [1024][64]
    float* __restrict__ cT,                        // [1024][64] in-place
    float* __restrict__ hT_copy)                   // optional h1T_all slice
{
    __shared__ float sx[CK * BATCH];      // 32 KB staging of activations
    __shared__ float gbuf[4][4 * BATCH];  // gate exchange: [gate][jj*64+b]

    const int tid  = threadIdx.x;
    const int lane = tid & 63;
    const int g    = tid >> 6;            // wave id == gate id (i,f,g,o)
    const int k0   = blockIdx.x * 4;      // hidden-unit base for this block

    float acc[4] = {0.f, 0.f, 0.f, 0.f};

    for (int part = 0; part < 2; ++part) {
        const float* src = part ? hT_in : xT;
        const float* W   = part ? W_hh  : W_ih;
        const int    K   = part ? HID   : Kx;

        const float* r0 = W + (size_t)(g * HID + k0 + 0) * K;
        const float* r1 = W + (size_t)(g * HID + k0 + 1) * K;
        const float* r2 = W + (size_t)(g * HID + k0 + 2) * K;
        const float* r3 = W + (size_t)(g * HID + k0 + 3) * K;

        for (int kb = 0; kb < K; kb += CK) {
            __syncthreads();
            // stage CK*64 contiguous floats -> LDS (coalesced float4)
            const float4* s4 = (const float4*)(src + (size_t)kb * BATCH);
            float4* d4 = (float4*)sx;
            #pragma unroll
            for (int i = 0; i < (CK * BATCH / 4) / 256; ++i)
                d4[i * 256 + tid] = s4[i * 256 + tid];
            __syncthreads();

            for (int kk = 0; kk < CK; kk += 4) {
                float4 w0 = *(const float4*)(r0 + kb + kk);
                float4 w1 = *(const float4*)(r1 + kb + kk);
                float4 w2 = *(const float4*)(r2 + kb + kk);
                float4 w3 = *(const float4*)(r3 + kb + kk);
                float x0 = sx[(kk + 0) * 64 + lane];
                float x1 = sx[(kk + 1) * 64 + lane];
                float x2 = sx[(kk + 2) * 64 + lane];
                float x3 = sx[(kk + 3) * 64 + lane];
                acc[0] += w0.x * x0 + w0.y * x1 + w0.z * x2 + w0.w * x3;
                acc[1] += w1.x * x0 + w1.y * x1 + w1.z * x2 + w1.w * x3;
                acc[2] += w2.x * x0 + w2.y * x1 + w2.z * x2 + w2.w * x3;
                acc[3] += w3.x * x0 + w3.y * x1 + w3.z * x2 + w3.w * x3;
            }
        }
    }

    // add biases, publish gates to LDS
    {
        const int j = g * HID + k0;
        #pragma unroll
        for (int jj = 0; jj < 4; ++jj)
            gbuf[g][jj * 64 + lane] = acc[jj] + b_ih[j + jj] + b_hh[j + jj];
    }
    __syncthreads();

    // cell update: wave g now handles hidden unit (k0+g), lane = batch
    {
        const int jj = g;
        const int b  = lane;
        float iv = gbuf[0][jj * 64 + b];
        float fv = gbuf[1][jj * 64 + b];
        float gv = gbuf[2][jj * 64 + b];
        float ov = gbuf[3][jj * 64 + b];
        iv = 1.f / (1.f + expf(-iv));
        fv = 1.f / (1.f + expf(-fv));
        gv = tanhf(gv);
        ov = 1.f / (1.f + expf(-ov));
        const int kidx = (k0 + jj) * 64 + b;
        float c = fv * cT[kidx] + iv * gv;
        float h = ov * tanhf(c);
        cT[kidx]     = c;
        hT_out[kidx] = h;
        if (hT_copy) hT_copy[kidx] = h;
    }
}

// ---------------------------------------------------------------------------
// Deferred output projection: out[t][b][v] = h1[t][b]·W_out[v] + b_out[v]
// A = h1T_all[t][k][b]; block computes one t (64 rows) x 64 vocab cols.
// Thread: v = v0 + lane (fixed), 16 b's = w*16 + m.  Coalesced stores along v.
// ---------------------------------------------------------------------------
__global__ __launch_bounds__(256) void out_gemm_kernel(
    const float* __restrict__ h1T_all, const float* __restrict__ W_out,
    const float* __restrict__ b_out, float* __restrict__ out)
{
    const int t  = blockIdx.x;
    const int v0 = blockIdx.y * 64;

    __shared__ float As[16 * 64];   // [kk][b]
    __shared__ float Bs[64][17];    // [v][kk] (+1 pad: conflict-free)

    const int tid  = threadIdx.x;
    const int lane = tid & 63;
    const int w    = tid >> 6;

    float acc[16];
    #pragma unroll
    for (int m = 0; m < 16; ++m) acc[m] = 0.f;

    const float* A = h1T_all + (size_t)t * HID * BATCH;

    for (int kb = 0; kb < HID; kb += 16) {
        __syncthreads();
        // As: 16 rows x 64 b = 1024 contiguous floats
        ((float4*)As)[tid] = ((const float4*)(A + (size_t)kb * BATCH))[tid];
        // Bs: 64 v-rows x 16 k
        {
            int i  = tid >> 2;
            int kc = (tid & 3) * 4;
            float4 wv = *(const float4*)(W_out + (size_t)(v0 + i) * HID + kb + kc);
            Bs[i][kc + 0] = wv.x; Bs[i][kc + 1] = wv.y;
            Bs[i][kc + 2] = wv.z; Bs[i][kc + 3] = wv.w;
        }
        __syncthreads();

        #pragma unroll
        for (int kk = 0; kk < 16; ++kk) {
            float wv = Bs[lane][kk];           // lane-varying v, pad-17 -> no conflict
            #pragma unroll
            for (int m = 0; m < 16; ++m)
                acc[m] += wv * As[kk * 64 + w * 16 + m];   // wave-uniform broadcast
        }
    }

    const float bo = b_out[v0 + lane];
    #pragma unroll
    for (int m = 0; m < 16; ++m) {
        int b = w * 16 + m;
        out[((size_t)t * BATCH + b) * VOCAB + v0 + lane] = acc[m] + bo;
    }
}

// ---------------------------------------------------------------------------
extern "C" void kernel_launch(void* const* d_in, const int* in_sizes, int n_in,
                              void* d_out, int out_size, void* d_ws, size_t ws_size,
                              hipStream_t stream)
{
    const int*   x     = (const int*)  d_in[0];
    const float* emb   = (const float*)d_in[1];
    const float* W_ih1 = (const float*)d_in[2];
    const float* W_hh1 = (const float*)d_in[3];
    const float* b_ih1 = (const float*)d_in[4];
    const float* b_hh1 = (const float*)d_in[5];
    const float* W_ih2 = (const float*)d_in[6];
    const float* W_hh2 = (const float*)d_in[7];
    const float* b_ih2 = (const float*)d_in[8];
    const float* b_hh2 = (const float*)d_in[9];
    const float* W_out = (const float*)d_in[10];
    const float* b_out = (const float*)d_in[11];
    float* out = (float*)d_out;

    float* ws    = (float*)d_ws;
    float* xeT   = ws + XET_OFF;
    float* h1all = ws + H1ALL_OFF;
    float* h0T[2] = { ws + STATE_OFF,            ws + STATE_OFF + HB_ };
    float* h1T[2] = { ws + STATE_OFF + 2 * HB_,  ws + STATE_OFF + 3 * HB_ };
    float* c0T    =   ws + STATE_OFF + 4 * HB_;
    float* c1T    =   ws + STATE_OFF + 5 * HB_;

    // zero-init h/c states (ws is poisoned 0xAA before timing)
    hipMemsetAsync(ws + STATE_OFF, 0, (size_t)6 * HB_ * sizeof(float), stream);

    // embedding gather (all timesteps), transposed layout
    embed_t_kernel<<<(TX * EMB * BATCH) / 256, 256, 0, stream>>>(x, emb, xeT);

    for (int t = 0; t < TX; ++t) {
        int pi = t & 1, po = pi ^ 1;
        lstm_step_kernel<<<HID / 4, 256, 0, stream>>>(
            xeT + (size_t)t * EMB * BATCH, EMB,
            h0T[pi], W_ih1, W_hh1, b_ih1, b_hh1,
            h0T[po], c0T, nullptr);
        lstm_step_kernel<<<HID / 4, 256, 0, stream>>>(
            h0T[po], HID,
            h1T[pi], W_ih2, W_hh2, b_ih2, b_hh2,
            h1T[po], c1T, h1all + (size_t)t * HID * BATCH);
    }

    dim3 og(TX, VOCAB / 64);
    out_gemm_kernel<<<og, 256, 0, stream>>>(h1all, W_out, b_out, out);
}

// Round 2
// 5580.467 us; speedup vs baseline: 9.1536x; 9.1536x over previous
//
#include <hip/hip_runtime.h>
#include <math.h>
#include <stdint.h>

#define VOCAB 2048
#define EMB   512
#define HID   1024
#define TX    256
#define BATCH 64
#define NBLK  256

typedef __attribute__((ext_vector_type(8))) short bf16x8;
typedef __attribute__((ext_vector_type(4))) float f32x4;
typedef unsigned int u32;
typedef unsigned short u16;
typedef __attribute__((ext_vector_type(4))) u32 u32x4;

// ---------------- ws byte offsets ----------------
// cnt     : barrier counter (monotonic, zeroed per launch)
// h0P     : 2 parity buffers, packed8 bf16 [128 kblk][64 b][8]
// h1P     : 257 slabs (slab t+1 = h1 at step t; slab 0 zeroed)
// xP      : [TX][64 kblk][64 b][8] bf16
// Wp      : per-block packed weights [256 blk][112 sec][4 grp][16 m][8] bf16
// bsum    : [2 layers][4][1024]  (b_ih + b_hh)
#define OFF_CNT 0u
#define OFF_H0  256u
#define OFF_H1  524288u
#define OFF_XP  34209792u
#define OFF_WP  50987008u
#define OFF_BS  80347136u

__device__ __forceinline__ u16 f2bf(float x){
  u32 v = __float_as_uint(x);
  v += 0x7fffu + ((v >> 16) & 1u);          // RNE
  return (u16)(v >> 16);
}
__device__ __forceinline__ float bf2f(u16 h){ return __uint_as_float(((u32)h) << 16); }
__device__ __forceinline__ u32 pack2(float a, float b){
  return (u32)f2bf(a) | ((u32)f2bf(b) << 16);
}
__device__ __forceinline__ float sigm(float x){ return 1.f/(1.f+__expf(-x)); }
__device__ __forceinline__ float tanh_(float x){
  float e = __expf(2.f*fabsf(x));           // overflow-safe: e=inf -> 1
  return copysignf(1.f - 2.f/(e+1.f), x);
}

// ---------------------------------------------------------------------------
// xP[t][kblk][b][i] = bf16(emb[x[b][t]][kblk*8+i])
// ---------------------------------------------------------------------------
__global__ __launch_bounds__(256) void embed_pack(
    const int* __restrict__ x, const float* __restrict__ emb, u32x4* __restrict__ xP)
{
  int flat = blockIdx.x*256 + threadIdx.x;   // t*4096 + kblk*64 + b
  int b    = flat & 63;
  int kblk = (flat >> 6) & 63;
  int t    = flat >> 12;
  int idx  = x[b*TX + t];
  const float* src = emb + (size_t)idx*EMB + kblk*8;
  u32x4 o;
  o.x = pack2(src[0], src[1]);
  o.y = pack2(src[2], src[3]);
  o.z = pack2(src[4], src[5]);
  o.w = pack2(src[6], src[7]);
  xP[flat] = o;
}

// ---------------------------------------------------------------------------
// Wp flat 16B index = ((blk*112 + s)*4 + grp)*16 + m
//   m = u*4 + gate  (u = unit-in-block 0..3, gate = i/f/g/o)
//   sections: s<16 -> W_ih1 (K=512); <48 -> W_hh1; <80 -> W_ih2; else W_hh2
//   element i of the 16B chunk = W[gate*1024 + blk*4 + u][ks*32 + grp*8 + i]
// ---------------------------------------------------------------------------
__global__ __launch_bounds__(256) void w_pack(
    const float* __restrict__ Wih1, const float* __restrict__ Whh1,
    const float* __restrict__ Wih2, const float* __restrict__ Whh2,
    u32x4* __restrict__ Wp)
{
  int flat = blockIdx.x*256 + threadIdx.x;   // 7168*256 threads exactly
  int m    = flat & 15;
  int grp  = (flat >> 4) & 3;
  int bs_  = flat >> 6;
  int blk  = bs_ / 112;
  int s    = bs_ - blk*112;
  const float* W; int K, ks;
  if      (s < 16){ W = Wih1; K = 512;  ks = s;      }
  else if (s < 48){ W = Whh1; K = 1024; ks = s - 16; }
  else if (s < 80){ W = Wih2; K = 1024; ks = s - 48; }
  else            { W = Whh2; K = 1024; ks = s - 80; }
  int u = m >> 2, r = m & 3;
  int row = r*HID + blk*4 + u;
  const float* src = W + (size_t)row*K + ks*32 + grp*8;
  u32x4 o;
  o.x = pack2(src[0], src[1]);
  o.y = pack2(src[2], src[3]);
  o.z = pack2(src[4], src[5]);
  o.w = pack2(src[6], src[7]);
  Wp[flat] = o;
}

__global__ __launch_bounds__(256) void bias_pack(
    const float* __restrict__ bi1, const float* __restrict__ bh1,
    const float* __restrict__ bi2, const float* __restrict__ bh2,
    float* __restrict__ bsum)
{
  int j = blockIdx.x*256 + threadIdx.x;      // 8192 threads
  if (j < 4096) bsum[j] = bi1[j] + bh1[j];
  else          bsum[j] = bi2[j-4096] + bh2[j-4096];
}

// ---------------------------------------------------------------------------
// Persistent 2-layer LSTM over all TX steps. 256 blocks (1/CU), 4 waves.
// Block owns 4 hidden units (16 gate-rows) of both layers; weights in LDS.
// Wave w handles batches 16w..16w+15 (MFMA N-tile). Lane l: batch
// b=16w+(l&15); its 4 C regs are gates i,f,g,o of unit blk*4+(l>>4).
// One grid barrier per step (between L1 h0-write and L2 h0-read).
// ---------------------------------------------------------------------------
#define MFMA_STEP(ACC, AIDX, BPTR, BIDX)                                        \
  { u32x4 a_ = sW[AIDX]; u32x4 b_ = (BPTR)[BIDX];                               \
    ACC = __builtin_amdgcn_mfma_f32_16x16x32_bf16(                              \
        *(bf16x8*)&a_, *(bf16x8*)&b_, ACC, 0, 0, 0); }

__global__ __launch_bounds__(256, 1) void lstm_persist(
    const u32x4* __restrict__ xP, u16* __restrict__ h0P, u16* __restrict__ h1P,
    const u32x4* __restrict__ Wp, const float* __restrict__ bsum,
    int* __restrict__ cnt)
{
  __shared__ u32x4 sW[7168];                  // 112 KB
  const int tid = threadIdx.x;
  const int blk = blockIdx.x;
  { const u32x4* g = Wp + (size_t)blk*7168;
    for (int i = tid; i < 7168; i += 256) sW[i] = g[i]; }

  const int w    = tid >> 6, l = tid & 63;
  const int grp  = l >> 4,  col = l & 15;
  const int b    = w*16 + col;
  const int unit = blk*4 + grp;
  const int aoff = grp*16 + col;              // + s*64   (LDS, u32x4 units)
  const int boff = grp*64 + b;                // + s*256  (global, u32x4 units)
  const int hwo  = (unit >> 3)*512 + b*8 + (unit & 7);  // h write elem offset

  float bs1[4], bs2[4];
  #pragma unroll
  for (int r = 0; r < 4; ++r){
    bs1[r] = bsum[r*HID + unit];
    bs2[r] = bsum[4096 + r*HID + unit];
  }
  float c0 = 0.f, c1 = 0.f;
  const u32x4* h04 = (const u32x4*)h0P;
  const u32x4* h14 = (const u32x4*)h1P;
  __syncthreads();

  for (int t = 0; t < TX; ++t){
    const int pin = t & 1, pout = pin ^ 1;
    // ---- LAYER 1 ----
    f32x4 acc0 = {0,0,0,0}, acc1 = {0,0,0,0};
    {
      const u32x4* Bx = xP + (size_t)t*4096;
      #pragma unroll
      for (int s = 0; s < 16; s += 2){
        MFMA_STEP(acc0, s*64 + aoff,      Bx, s*256 + boff);
        MFMA_STEP(acc1, (s+1)*64 + aoff,  Bx, (s+1)*256 + boff);
      }
      const u32x4* Bh = h04 + pin*8192;
      #pragma unroll
      for (int s = 0; s < 32; s += 2){
        MFMA_STEP(acc0, (16+s)*64 + aoff, Bh, s*256 + boff);
        MFMA_STEP(acc1, (17+s)*64 + aoff, Bh, (s+1)*256 + boff);
      }
    }
    {
      float p0 = acc0[0]+acc1[0]+bs1[0];
      float p1 = acc0[1]+acc1[1]+bs1[1];
      float p2 = acc0[2]+acc1[2]+bs1[2];
      float p3 = acc0[3]+acc1[3]+bs1[3];
      float iv = sigm(p0), fv = sigm(p1), gv = tanh_(p2), ov = sigm(p3);
      c0 = fv*c0 + iv*gv;
      h0P[(u32)pout*65536u + hwo] = f2bf(ov*tanh_(c0));
    }
    // ---- grid barrier (one per step) ----
    __syncthreads();
    if (tid == 0){
      __hip_atomic_fetch_add(cnt, 1, __ATOMIC_RELEASE, __HIP_MEMORY_SCOPE_AGENT);
      const int target = NBLK*(t+1);
      while (__hip_atomic_load(cnt, __ATOMIC_ACQUIRE, __HIP_MEMORY_SCOPE_AGENT) < target)
        __builtin_amdgcn_s_sleep(2);
    }
    __syncthreads();
    // ---- LAYER 2 ----
    f32x4 d0 = {0,0,0,0}, d1 = {0,0,0,0};
    {
      const u32x4* Bh0 = h04 + pout*8192;          // new h0
      #pragma unroll
      for (int s = 0; s < 32; s += 2){
        MFMA_STEP(d0, (48+s)*64 + aoff, Bh0, s*256 + boff);
        MFMA_STEP(d1, (49+s)*64 + aoff, Bh0, (s+1)*256 + boff);
      }
      const u32x4* Bh1 = h14 + (size_t)t*8192;     // h1(t-1)
      #pragma unroll
      for (int s = 0; s < 32; s += 2){
        MFMA_STEP(d0, (80+s)*64 + aoff, Bh1, s*256 + boff);
        MFMA_STEP(d1, (81+s)*64 + aoff, Bh1, (s+1)*256 + boff);
      }
    }
    {
      float p0 = d0[0]+d1[0]+bs2[0];
      float p1 = d0[1]+d1[1]+bs2[1];
      float p2 = d0[2]+d1[2]+bs2[2];
      float p3 = d0[3]+d1[3]+bs2[3];
      float iv = sigm(p0), fv = sigm(p1), gv = tanh_(p2), ov = sigm(p3);
      c1 = fv*c1 + iv*gv;
      h1P[(size_t)(t+1)*65536u + hwo] = f2bf(ov*tanh_(c1));
    }
  }
}

// ---------------------------------------------------------------------------
// out[t][b][v] = sum_k h1(t)[k][b] * W_out[v][k] + b_out[v]
// A from bf16 packed slab (t+1); W_out/accum fp32 (accuracy-preserving).
// ---------------------------------------------------------------------------
__global__ __launch_bounds__(256) void out_gemm(
    const u16* __restrict__ h1P, const float* __restrict__ W_out,
    const float* __restrict__ b_out, float* __restrict__ out)
{
  const int t  = blockIdx.x;
  const int v0 = blockIdx.y * 64;

  __shared__ float As[16*64];
  __shared__ float Bs[64][17];

  const int tid = threadIdx.x, lane = tid & 63, w = tid >> 6;
  float acc[16];
  #pragma unroll
  for (int m = 0; m < 16; ++m) acc[m] = 0.f;

  const u16* hs = h1P + (size_t)(t+1)*65536u;

  for (int kb = 0; kb < HID; kb += 16){
    __syncthreads();
    {
      const u32* src = (const u32*)(hs + (kb >> 3)*512);  // 1024 bf16 chunk
      u32 p0 = src[tid*2], p1 = src[tid*2+1];
      int e   = tid*4;
      int i0  = e & 7;
      int bb  = (e >> 3) & 63;
      int kk  = (e >> 9)*8 + i0;
      As[(kk+0)*64 + bb] = bf2f((u16)(p0 & 0xffffu));
      As[(kk+1)*64 + bb] = bf2f((u16)(p0 >> 16));
      As[(kk+2)*64 + bb] = bf2f((u16)(p1 & 0xffffu));
      As[(kk+3)*64 + bb] = bf2f((u16)(p1 >> 16));
    }
    {
      int i = tid >> 2, kc = (tid & 3)*4;
      float4 wv = *(const float4*)(W_out + (size_t)(v0+i)*HID + kb + kc);
      Bs[i][kc+0] = wv.x; Bs[i][kc+1] = wv.y;
      Bs[i][kc+2] = wv.z; Bs[i][kc+3] = wv.w;
    }
    __syncthreads();

    #pragma unroll
    for (int kk = 0; kk < 16; ++kk){
      float wv = Bs[lane][kk];
      #pragma unroll
      for (int m = 0; m < 16; ++m)
        acc[m] += wv * As[kk*64 + w*16 + m];
    }
  }

  const float bo = b_out[v0 + lane];
  #pragma unroll
  for (int m = 0; m < 16; ++m){
    int bb = w*16 + m;
    out[((size_t)t*BATCH + bb)*VOCAB + v0 + lane] = acc[m] + bo;
  }
}

// ---------------------------------------------------------------------------
extern "C" void kernel_launch(void* const* d_in, const int* in_sizes, int n_in,
                              void* d_out, int out_size, void* d_ws, size_t ws_size,
                              hipStream_t stream)
{
  const int*   x     = (const int*)  d_in[0];
  const float* emb   = (const float*)d_in[1];
  const float* W_ih1 = (const float*)d_in[2];
  const float* W_hh1 = (const float*)d_in[3];
  const float* b_ih1 = (const float*)d_in[4];
  const float* b_hh1 = (const float*)d_in[5];
  const float* W_ih2 = (const float*)d_in[6];
  const float* W_hh2 = (const float*)d_in[7];
  const float* b_ih2 = (const float*)d_in[8];
  const float* b_hh2 = (const float*)d_in[9];
  const float* W_out = (const float*)d_in[10];
  const float* b_out = (const float*)d_in[11];
  float* out = (float*)d_out;

  char* ws = (char*)d_ws;
  int*   cnt  = (int*)  (ws + OFF_CNT);
  u16*   h0P  = (u16*)  (ws + OFF_H0);
  u16*   h1P  = (u16*)  (ws + OFF_H1);
  u32x4* xP   = (u32x4*)(ws + OFF_XP);
  u32x4* Wp   = (u32x4*)(ws + OFF_WP);
  float* bsum = (float*)(ws + OFF_BS);

  // zero: cnt + both h0 parities + h1 slab 0 (all inside first 655360 B)
  hipMemsetAsync(d_ws, 0, 655360, stream);

  embed_pack<<<4096, 256, 0, stream>>>(x, emb, xP);
  w_pack<<<7168, 256, 0, stream>>>(W_ih1, W_hh1, W_ih2, W_hh2, Wp);
  bias_pack<<<32, 256, 0, stream>>>(b_ih1, b_hh1, b_ih2, b_hh2, bsum);

  lstm_persist<<<NBLK, 256, 0, stream>>>(xP, h0P, h1P, Wp, bsum, cnt);

  dim3 og(TX, VOCAB/64);
  out_gemm<<<og, 256, 0, stream>>>(h1P, W_out, b_out, out);
}